// Round 4
// baseline (12090.749 us; speedup 1.0000x reference)
//
#include <hip/hip_runtime.h>
#include <math.h>

// ESN reservoir, persistent kernel, round 22: staggered dual-chain phases +
// poll-prefetch. r21 (6761us) post-mortem: step = 7920cy, compute only
// ~2000cy; the rest is exchange latency that is SERIAL because the poll
// load can only issue when the consumer arrives (1 RT) after store
// visibility (~900-1500cy). The two batches of a block's pair are
// INDEPENDENT recurrences -> split into two phases per iteration and
// prefetch each chain's tagged loads during the other chain's compute:
//   phase A: wait pfA (reg check) -> stage -> sync -> issue pfB(t) ->
//            dot(b0) -> reduce -> tanh -> tagged stores -> projection(b0)
//   phase B: wait pfB -> stage -> sync -> dot(b1) -> issue pfA(t+1) ->
//            reduce -> tanh -> tagged stores -> projection(b1)
// The UC round-trip hides under ~1200-2000cy of the other chain's compute.
// Cost: W granule ds_reads no longer shared across batches (+16/wave/step).
//
// Protocol (verified r19/r21): tagged dword = 2x int8 payload + 16-bit tag
// (= step); dword stores atomic => tag certifies payload. No drain, no
// flags. Buffer reuse safe per chain by 2-step induction. Bounded spins:
// worst case wrong answer, never a hang.
// In-flight prefetch regs use "+v"-tied s_waitcnt (T14 discipline) so the
// compiler cannot copy/spill them before the wait.

#define RDIM   2048
#define BATCH  16
#define TSTEPS 2048
#define NIN    3
#define NOUT   3
#define NBLK   256
#define NTHR   512

typedef unsigned u32x2 __attribute__((ext_vector_type(2)));

// workspace layout (dwords)
#define HT0_DW     0            // [8 groups][2 batches][1024] tagged h dwords
#define HT1_DW     16384
#define WS_USED_DW 32768

#define POLL_MAX   (1L << 16)

// UC tagged-dword ops (device coherence point)
__device__ __forceinline__ void ld2_issue(u32x2& d, const unsigned* p) {
    asm volatile("global_load_dwordx2 %0, %1, off sc0 sc1"
                 : "=v"(d) : "v"(p) : "memory");
}
__device__ __forceinline__ void pf_wait(u32x2& d) {
    asm volatile("s_waitcnt vmcnt(0)" : "+v"(d) :: "memory");
}
__device__ __forceinline__ void ld2_uc(u32x2& d, const unsigned* p) {
    asm volatile("global_load_dwordx2 %0, %1, off sc0 sc1\n\ts_waitcnt vmcnt(0)"
                 : "=v"(d) : "v"(p) : "memory");
}
__device__ __forceinline__ void st1_uc(unsigned* p, unsigned v) {
    asm volatile("global_store_dword %0, %1, off sc0 sc1" :: "v"(p), "v"(v) : "memory");
}

__device__ __forceinline__ int q8(float v) {          // round, clamp [-127,127]
    float c = fminf(127.f, fmaxf(-127.f, v));
    return (int)__builtin_rintf(c);
}
__device__ __forceinline__ unsigned pack4(int a, int b, int c, int d) {
    return (a & 0xff) | ((b & 0xff) << 8) | ((c & 0xff) << 16) | ((d & 0xff) << 24);
}
__device__ __forceinline__ int dot4i(unsigned a, unsigned b, int c) {
#if __has_builtin(__builtin_amdgcn_sdot4)
    return __builtin_amdgcn_sdot4((int)a, (int)b, c, false);
#else
    c += (int)(signed char)(a) * (int)(signed char)(b);
    c += (int)(signed char)(a >> 8)  * (int)(signed char)(b >> 8);
    c += (int)(signed char)(a >> 16) * (int)(signed char)(b >> 16);
    c += (int)(signed char)(a >> 24) * (int)(signed char)(b >> 24);
    return c;
#endif
}
__device__ __forceinline__ int dot16(uint4 wq, uint4 hq, int c) {
    c = dot4i(wq.x, hq.x, c);
    c = dot4i(wq.y, hq.y, c);
    c = dot4i(wq.z, hq.z, c);
    c = dot4i(wq.w, hq.w, c);
    return c;
}
// per-lane poll: first check uses already-waited prefetch regs
__device__ __forceinline__ void poll_pair(u32x2& d, const unsigned* p, unsigned tg) {
    long r = 0;
    for (;;) {
        bool ok = (d[0] >> 16) == tg && (d[1] >> 16) == tg;
        if (ok || r > POLL_MAX) break;            // per-lane exit; never hangs
        ++r;
        if (r > 64) __builtin_amdgcn_s_sleep(1);
        ld2_uc(d, p);
    }
}

extern "C" __global__ void __launch_bounds__(NTHR, 1) esn_persist(
    const float* __restrict__ W,       // [R,R] fp32
    const float* __restrict__ Win,     // [R,3]
    const float* __restrict__ x,       // [B,T,3]
    const float* __restrict__ Wout,    // [3,R]
    const float* __restrict__ bout,    // [3]
    unsigned* wsu,                     // workspace (dwords, see layout)
    float* __restrict__ out)           // [B,T,3]
{
    __shared__ __align__(16) unsigned hs2[2][512];  // 2x2KB detagged h int8 per batch
    __shared__ int  red[8][544];                    // transpose-reduce (int partials)
    __shared__ float wscale[64];                    // per-row W scale (m/127)
    extern __shared__ unsigned wlds[];              // 128 KB: W int8 [64 rows][512 dw]

    const int tid  = threadIdx.x;
    const int lane = tid & 63;
    const int w    = tid >> 6;                      // wave 0..7
    const int blk  = blockIdx.x;
    const int rg   = blk & 31;                      // rows rg*64..+64
    const int g    = blk >> 5;                      // batches g*2..+2
    const int rbase = rg * 64 + w * 8;              // wave's 8 rows
    const int b0    = g * 2;

    // ---- one-time: quantize W rows -> LDS int8 (per-row scale) ----
#pragma unroll
    for (int rr = 0; rr < 8; ++rr) {
        const int   row = rbase + rr;
        const float4* Wr = (const float4*)(W + (size_t)row * RDIM);
        float m = 0.f;
#pragma unroll
        for (int j = 0; j < 8; ++j) {               // lane covers 8 float4 = 32 elems
            float4 v = Wr[j * 64 + lane];
            m = fmaxf(m, fmaxf(fmaxf(fabsf(v.x), fabsf(v.y)),
                               fmaxf(fabsf(v.z), fabsf(v.w))));
        }
#pragma unroll
        for (int off = 32; off >= 1; off >>= 1)
            m = fmaxf(m, __shfl_xor(m, off, 64));
        const float inv = (m > 0.f) ? 127.f / m : 0.f;
        if (lane == 0) wscale[w * 8 + rr] = (m > 0.f) ? m / 127.f : 0.f;
#pragma unroll
        for (int j = 0; j < 8; ++j) {
            float4 v = Wr[j * 64 + lane];
            wlds[(w * 8 + rr) * 512 + j * 64 + lane] =
                pack4(q8(v.x * inv), q8(v.y * inv), q8(v.z * inv), q8(v.w * inv));
        }
    }
    __syncthreads();

    unsigned* const ht0 = wsu + HT0_DW;
    unsigned* const ht1 = wsu + HT1_DW;

    u32x2 pfA, pfB;
    // bootstrap: prefetch A[0] (memset zeros = tag 0 + zero payload = h0)
    ld2_issue(pfA, ht0 + g * 2048 + tid * 2);

    for (int t = 0; t <= TSTEPS; ++t) {
        unsigned* const hb  = (t & 1) ? ht1 : ht0;       // tags == t live here
        unsigned* const hbn = (t & 1) ? ht0 : ht1;       // t+1 stores go here
        const unsigned tg  = (unsigned)t & 0xffffu;
        const unsigned tg1 = (unsigned)(t + 1) & 0xffffu;

        // ================= PHASE A (batch b0) =================
        {
            pf_wait(pfA);
            poll_pair(pfA, hb + g * 2048 + tid * 2, tg);
            hs2[0][tid] = (pfA[0] & 0xffffu) | (pfA[1] << 16);
            __syncthreads();                         // A staged

            // issue pfB for B[t] (stored ~1 full iteration ago -> fresh);
            // flies during A's dot.
            ld2_issue(pfB, hb + g * 2048 + 1024 + tid * 2);

            if (t < TSTEPS) {
                int acc[8];
#pragma unroll
                for (int r = 0; r < 8; ++r) acc[r] = 0;
                const uint4* h4 = (const uint4*)hs2[0];
                uint4 h0 = h4[lane];                 // k = 16*lane..+16
                uint4 h1 = h4[64 + lane];            // k = 1024+16*lane..+16
                const uint4* w4p = (const uint4*)wlds;
#pragma unroll
                for (int rr = 0; rr < 8; ++rr) {
                    const int wb = (w * 8 + rr) * 128;
                    uint4 w0 = w4p[wb + lane];
                    uint4 w1 = w4p[wb + 64 + lane];
                    acc[rr] = dot16(w0, h0, acc[rr]);
                    acc[rr] = dot16(w1, h1, acc[rr]);
                }
                // fold 32, swizzled transpose, sum 32 (int exact)
                int v[8];
#pragma unroll
                for (int i = 0; i < 8; ++i)
                    v[i] = acc[i] + __shfl_xor(acc[i], 32, 64);
                if (lane < 32) {
#pragma unroll
                    for (int i = 0; i < 8; ++i)
                        red[w][lane * 17 + ((i + lane) & 7)] = v[i];
                }
                __syncthreads();
                int qv = 0;
                if (lane < 8) {
                    int s = 0;
#pragma unroll
                    for (int l = 0; l < 32; ++l)
                        s += red[w][l * 17 + ((lane + l) & 7)];
                    const int row = rbase + lane;
                    float pre = (float)s * wscale[w * 8 + lane] * (1.f / 127.f);
#pragma unroll
                    for (int c = 0; c < NIN; ++c)
                        pre += Win[row * NIN + c] *
                               x[((size_t)b0 * TSTEPS + t) * NIN + c];
                    qv = q8(tanhf(pre) * 127.f);
                }
                int qlo = __shfl(qv, 2 * (lane & 3), 64);
                int qhi = __shfl(qv, 2 * (lane & 3) + 1, 64);
                if (lane < 4) {
                    unsigned dv = (unsigned)(qlo & 0xff) |
                                  ((unsigned)(qhi & 0xff) << 8) | (tg1 << 16);
                    st1_uc(hbn + g * 2048 + 0 * 1024 + rg * 32 + w * 4 + lane, dv);
                }
            }
            // projection of batch b0's staged h (tag t) by rotating block
            if (t > 0 && rg == ((t - 1) & 31) && w < 3) {
                const signed char* hsv = (const signed char*)hs2[0];
                const int o = t - 1, k = w;
                float a = 0.f;
#pragma unroll
                for (int j = 0; j < 32; ++j) {
                    const int r = j * 64 + lane;
                    a += (float)hsv[r] * Wout[k * RDIM + r];
                }
#pragma unroll
                for (int off = 32; off >= 1; off >>= 1)
                    a += __shfl_xor(a, off, 64);
                if (lane == 0)
                    out[((size_t)b0 * TSTEPS + o) * NOUT + k] =
                        a * (1.f / 127.f) + bout[k];
            }
        }

        // ================= PHASE B (batch b0+1) =================
        {
            pf_wait(pfB);
            poll_pair(pfB, hb + g * 2048 + 1024 + tid * 2, tg);
            hs2[1][tid] = (pfB[0] & 0xffffu) | (pfB[1] << 16);
            __syncthreads();                         // B staged (also fences
                                                     // A's red-reads vs B's red-writes)
            if (t < TSTEPS) {
                int acc[8];
#pragma unroll
                for (int r = 0; r < 8; ++r) acc[r] = 0;
                const uint4* h4 = (const uint4*)hs2[1];
                uint4 h0 = h4[lane];
                uint4 h1 = h4[64 + lane];
                const uint4* w4p = (const uint4*)wlds;
#pragma unroll
                for (int rr = 0; rr < 8; ++rr) {
                    const int wb = (w * 8 + rr) * 128;
                    uint4 w0 = w4p[wb + lane];
                    uint4 w1 = w4p[wb + 64 + lane];
                    acc[rr] = dot16(w0, h0, acc[rr]);
                    acc[rr] = dot16(w1, h1, acc[rr]);
                }
                // issue pfA for A[t+1]: A's stores are ~(stage+dot) old here,
                // visible even with producer skew; returns before next A-check.
                ld2_issue(pfA, hbn + g * 2048 + tid * 2);

                int v[8];
#pragma unroll
                for (int i = 0; i < 8; ++i)
                    v[i] = acc[i] + __shfl_xor(acc[i], 32, 64);
                if (lane < 32) {
#pragma unroll
                    for (int i = 0; i < 8; ++i)
                        red[w][lane * 17 + ((i + lane) & 7)] = v[i];
                }
                __syncthreads();
                int qv = 0;
                if (lane < 8) {
                    int s = 0;
#pragma unroll
                    for (int l = 0; l < 32; ++l)
                        s += red[w][l * 17 + ((lane + l) & 7)];
                    const int row = rbase + lane;
                    float pre = (float)s * wscale[w * 8 + lane] * (1.f / 127.f);
#pragma unroll
                    for (int c = 0; c < NIN; ++c)
                        pre += Win[row * NIN + c] *
                               x[((size_t)(b0 + 1) * TSTEPS + t) * NIN + c];
                    qv = q8(tanhf(pre) * 127.f);
                }
                int qlo = __shfl(qv, 2 * (lane & 3), 64);
                int qhi = __shfl(qv, 2 * (lane & 3) + 1, 64);
                if (lane < 4) {
                    unsigned dv = (unsigned)(qlo & 0xff) |
                                  ((unsigned)(qhi & 0xff) << 8) | (tg1 << 16);
                    st1_uc(hbn + g * 2048 + 1 * 1024 + rg * 32 + w * 4 + lane, dv);
                }
            }
            // projection of batch b0+1's staged h (tag t) by rotating block
            if (t > 0 && rg == ((t - 1) & 31) && w < 3) {
                const signed char* hsv = (const signed char*)hs2[1];
                const int o = t - 1, k = w;
                float a = 0.f;
#pragma unroll
                for (int j = 0; j < 32; ++j) {
                    const int r = j * 64 + lane;
                    a += (float)hsv[r] * Wout[k * RDIM + r];
                }
#pragma unroll
                for (int off = 32; off >= 1; off >>= 1)
                    a += __shfl_xor(a, off, 64);
                if (lane == 0)
                    out[((size_t)(b0 + 1) * TSTEPS + o) * NOUT + k] =
                        a * (1.f / 127.f) + bout[k];
            }
        }
        // No end-of-loop barrier needed: hs2 buffers are per-phase; next
        // write to hs2[0] (iter t+1, phase A stage) is separated from this
        // iteration's hs2[0] readers by phase B's stage barrier, and hs2[1]
        // readers by iter t+1's phase A barriers. red writers/readers are
        // fenced by the interleaving stage barriers.
    }
}

extern "C" void kernel_launch(void* const* d_in, const int* in_sizes, int n_in,
                              void* d_out, int out_size, void* d_ws, size_t ws_size,
                              hipStream_t stream) {
    const float* x    = (const float*)d_in[0];
    const float* Win  = (const float*)d_in[1];
    const float* W    = (const float*)d_in[2];
    const float* Wout = (const float*)d_in[3];
    const float* bout = (const float*)d_in[4];
    float* out = (float*)d_out;
    unsigned* wsu = (unsigned*)d_ws;

    // zero tagged-h buffers (tag0 + zero payload = valid h0), ~128 KB
    hipMemsetAsync(d_ws, 0, (size_t)WS_USED_DW * sizeof(unsigned), stream);

    // allow 128 KB dynamic LDS (idempotent; same work every call)
    hipFuncSetAttribute((const void*)esn_persist,
                        hipFuncAttributeMaxDynamicSharedMemorySize, 131072);

    void* args[] = {(void*)&W, (void*)&Win, (void*)&x, (void*)&Wout, (void*)&bout,
                    (void*)&wsu, (void*)&out};
    hipError_t e = hipLaunchCooperativeKernel((const void*)esn_persist,
                                              dim3(NBLK), dim3(NTHR),
                                              args, 131072, stream);
    if (e != hipSuccess) {
        // Fallback: plain launch (256 blocks, 1/CU with ~150KB LDS -> all
        // co-resident; bounded spins guarantee no hang regardless).
        esn_persist<<<dim3(NBLK), dim3(NTHR), 131072, stream>>>(
            W, Win, x, Wout, bout, wsu, out);
    }
}

// Round 5
// 7676.740 us; speedup vs baseline: 1.5750x; 1.5750x over previous
//
#include <hip/hip_runtime.h>
#include <math.h>

// ESN reservoir, persistent kernel, round 23: k-split waves, register
// exchange via ds_bpermute, one barrier/step.
//
// r22 post-mortem (12.1ms): two staggered phases = two serial UC gates per
// step + stale prefetches under skew. Reverted.
// r21 analysis (6.76ms, 7920cy/step): compute 2000cy; exchange 5900cy of
// which the stage->barrier->LDS-reload hop couples every wave to the max
// over ALL 32 producers before any dot starts.
//
// r23 structure (one fused step, tagged protocol unchanged from r21):
//  - wave w owns k-slice [256w,256w+256). Lane l polls ONE producer's
//    4-value window per batch (2x 8B tagged loads). Wave's dot needs only
//    its 4 producers, not 32; skew absorbed behind the dot.
//  - h window redistribution in-register: 16 ds_bpermute (no LDS staging,
//    no pre-dot barrier).
//  - partial dots fold over kslot with 3 shfl_xor; ONE __syncthreads into
//    double-buffered red[2]; waves 0-1 final-sum 8 partials, tanh, tagged
//    stores (wire format identical to r21); waves 2-7 do the rotating
//    projection in parallel from double-buffered hstage[2].
//  - WAR safety: step-t reads of red/hstage[par] happen between barrier(t)
//    and barrier(t+1); next writes to parity par occur at t+2 after
//    barrier(t+1) => ordered. hstage writes(t) vs reads(t) ordered by
//    barrier(t).
//  - int32 dot is exact => h trajectory bit-identical to r16/r21.
//  - bounded spins: worst case wrong answer, never a hang.

#define RDIM   2048
#define BATCH  16
#define TSTEPS 2048
#define NIN    3
#define NOUT   3
#define NBLK   256
#define NTHR   512

typedef unsigned u32x2 __attribute__((ext_vector_type(2)));

// workspace layout (dwords)
#define HT0_DW     0            // [8 groups][2 batches][1024] tagged h dwords
#define HT1_DW     16384
#define WS_USED_DW 32768

#define POLL_MAX   (1L << 16)

__device__ __forceinline__ void st1_uc(unsigned* p, unsigned v) {
    asm volatile("global_store_dword %0, %1, off sc0 sc1" :: "v"(p), "v"(v) : "memory");
}

__device__ __forceinline__ int q8(float v) {          // round, clamp [-127,127]
    float c = fminf(127.f, fmaxf(-127.f, v));
    return (int)__builtin_rintf(c);
}
__device__ __forceinline__ unsigned pack4(int a, int b, int c, int d) {
    return (a & 0xff) | ((b & 0xff) << 8) | ((c & 0xff) << 16) | ((d & 0xff) << 24);
}
__device__ __forceinline__ int dot4i(unsigned a, unsigned b, int c) {
#if __has_builtin(__builtin_amdgcn_sdot4)
    return __builtin_amdgcn_sdot4((int)a, (int)b, c, false);
#else
    c += (int)(signed char)(a) * (int)(signed char)(b);
    c += (int)(signed char)(a >> 8)  * (int)(signed char)(b >> 8);
    c += (int)(signed char)(a >> 16) * (int)(signed char)(b >> 16);
    c += (int)(signed char)(a >> 24) * (int)(signed char)(b >> 24);
    return c;
#endif
}
__device__ __forceinline__ int dot16(uint4 wq, uint4 hq, int c) {
    c = dot4i(wq.x, hq.x, c);
    c = dot4i(wq.y, hq.y, c);
    c = dot4i(wq.z, hq.z, c);
    c = dot4i(wq.w, hq.w, c);
    return c;
}

extern "C" __global__ void __launch_bounds__(NTHR, 1) esn_persist(
    const float* __restrict__ W,       // [R,R] fp32
    const float* __restrict__ Win,     // [R,3]
    const float* __restrict__ x,       // [B,T,3]
    const float* __restrict__ Wout,    // [3,R]
    const float* __restrict__ bout,    // [3]
    unsigned* wsu,                     // workspace (dwords, see layout)
    float* __restrict__ out)           // [B,T,3]
{
    __shared__ int red[2][8][8][16];         // [parity][wave][rgrp][rr*2+b] 8KB
    __shared__ unsigned hstage[2][2][512];   // [parity][batch][payload dw] 8KB
    __shared__ float wscale[64];             // per-row W scale (m/127)
    extern __shared__ unsigned wlds[];       // 128 KB: W int8 [64 rows][512 dw]

    const int tid  = threadIdx.x;
    const int lane = tid & 63;
    const int w    = tid >> 6;               // wave 0..7
    const int blk  = blockIdx.x;
    const int rg   = blk & 31;               // rows rg*64..+64
    const int g    = blk >> 5;               // batches g*2..+2
    const int b0    = g * 2;
    const int kslot = lane >> 3;             // 0..7: k sub-slice within wave
    const int rgrp  = lane & 7;              // 0..7: row octet within block

    // ---- one-time: quantize W rows -> LDS int8 (per-row scale), r21 verbatim
#pragma unroll
    for (int rr = 0; rr < 8; ++rr) {
        const int   row = rg * 64 + w * 8 + rr;
        const float4* Wr = (const float4*)(W + (size_t)row * RDIM);
        float m = 0.f;
#pragma unroll
        for (int j = 0; j < 8; ++j) {        // lane covers 8 float4 = 32 elems
            float4 v = Wr[j * 64 + lane];
            m = fmaxf(m, fmaxf(fmaxf(fabsf(v.x), fabsf(v.y)),
                               fmaxf(fabsf(v.z), fabsf(v.w))));
        }
#pragma unroll
        for (int off = 32; off >= 1; off >>= 1)
            m = fmaxf(m, __shfl_xor(m, off, 64));
        const float inv = (m > 0.f) ? 127.f / m : 0.f;
        if (lane == 0) wscale[w * 8 + rr] = (m > 0.f) ? m / 127.f : 0.f;
#pragma unroll
        for (int j = 0; j < 8; ++j) {
            float4 v = Wr[j * 64 + lane];
            wlds[(w * 8 + rr) * 512 + j * 64 + lane] =
                pack4(q8(v.x * inv), q8(v.y * inv), q8(v.z * inv), q8(v.w * inv));
        }
    }
    __syncthreads();

    unsigned* const ht0 = wsu + HT0_DW;
    unsigned* const ht1 = wsu + HT1_DW;

    for (int t = 0; t <= TSTEPS; ++t) {
        unsigned* const hb  = (t & 1) ? ht1 : ht0;   // tags == t live here
        unsigned* const hbn = (t & 1) ? ht0 : ht1;   // t+1 stores go here
        const unsigned tg  = (unsigned)t & 0xffffu;
        const unsigned tg1 = (unsigned)(t + 1) & 0xffffu;
        const int par = t & 1;

        // ---- poll: lane waits on its OWN 4-value window (1 producer/batch)
        // tagged uint2 per batch at [128w + 2*lane]; memset zeros = valid h0.
        u32x2 ta, tb;
        {
            const unsigned* pA = hb + g * 2048 +        128 * w + 2 * lane;
            const unsigned* pB = hb + g * 2048 + 1024 + 128 * w + 2 * lane;
            long r = 0;
            for (;;) {
                asm volatile("global_load_dwordx2 %0, %2, off sc0 sc1\n\t"
                             "global_load_dwordx2 %1, %3, off sc0 sc1\n\t"
                             "s_waitcnt vmcnt(0)"
                             : "=&v"(ta), "=&v"(tb) : "v"(pA), "v"(pB) : "memory");
                bool ok = (ta[0] >> 16) == tg && (ta[1] >> 16) == tg &&
                          (tb[0] >> 16) == tg && (tb[1] >> 16) == tg;
                if (ok || r > POLL_MAX) break;   // per-lane exit; never hangs
                ++r;
                if (r > 64) __builtin_amdgcn_s_sleep(1);
            }
        }
        // detag: payload dword (4 int8 h values) per batch
        const unsigned pdA = (ta[0] & 0xffffu) | (ta[1] << 16);
        const unsigned pdB = (tb[0] & 0xffffu) | (tb[1] << 16);
        // stage for projection (read after this step's barrier)
        hstage[par][0][(w << 6) + lane] = pdA;
        hstage[par][1][(w << 6) + lane] = pdB;

        if (t < TSTEPS) {
            // ---- assemble lane's 32-byte k-window in-register (no LDS hop):
            // lane (kslot,rgrp) gathers payload dwords of lanes kslot*8+j.
            const int sb = (lane & 0x38) << 2;       // byte idx of src lane 8*kslot
            unsigned ha[8], hbv[8];
#pragma unroll
            for (int j = 0; j < 8; ++j) {
                ha[j]  = (unsigned)__builtin_amdgcn_ds_bpermute(sb + 4 * j, (int)pdA);
                hbv[j] = (unsigned)__builtin_amdgcn_ds_bpermute(sb + 4 * j, (int)pdB);
            }
            const uint4 hA0 = make_uint4(ha[0], ha[1], ha[2], ha[3]);
            const uint4 hA1 = make_uint4(ha[4], ha[5], ha[6], ha[7]);
            const uint4 hB0 = make_uint4(hbv[0], hbv[1], hbv[2], hbv[3]);
            const uint4 hB1 = make_uint4(hbv[4], hbv[5], hbv[6], hbv[7]);

            // ---- partial dot: rows [8*rgrp..+8), k [256w+32*kslot..+32)
            int acc[8][2];
#pragma unroll
            for (int rr = 0; rr < 8; ++rr) { acc[rr][0] = 0; acc[rr][1] = 0; }
            const uint4* w4p = (const uint4*)wlds;
            const int gbase = (w << 4) + (kslot << 1);
#pragma unroll
            for (int rr = 0; rr < 8; ++rr) {
                const int gi = (((rgrp << 3) + rr) << 7) + gbase;
                uint4 w0 = w4p[gi];
                uint4 w1 = w4p[gi + 1];
                acc[rr][0] = dot16(w0, hA0, acc[rr][0]);
                acc[rr][0] = dot16(w1, hA1, acc[rr][0]);
                acc[rr][1] = dot16(w0, hB0, acc[rr][1]);
                acc[rr][1] = dot16(w1, hB1, acc[rr][1]);
            }
            // ---- fold kslot (lane bits 3..5); int add order-exact
#pragma unroll
            for (int rr = 0; rr < 8; ++rr)
#pragma unroll
                for (int b = 0; b < 2; ++b) {
                    int a = acc[rr][b];
                    a += __shfl_xor(a, 8, 64);
                    a += __shfl_xor(a, 16, 64);
                    a += __shfl_xor(a, 32, 64);
                    acc[rr][b] = a;
                }
            if (lane < 8) {                          // lane == rgrp, kslot 0
#pragma unroll
                for (int rr = 0; rr < 8; ++rr) {
                    red[par][w][lane][(rr << 1)]     = acc[rr][0];
                    red[par][w][lane][(rr << 1) + 1] = acc[rr][1];
                }
            }
        }
        __syncthreads();                             // the ONE barrier/step

        // ---- waves 0-1: final 8-way sum, tanh, tagged stores (r21 wire fmt)
        if (t < TSTEPS && tid < 128) {
            const int br = tid >> 1;                 // in-block row 0..63
            const int b  = tid & 1;
            int s = 0;
#pragma unroll
            for (int wp = 0; wp < 8; ++wp)
                s += red[par][wp][br >> 3][((br & 7) << 1) + b];
            float pre = (float)s * wscale[br] * (1.f / 127.f);
#pragma unroll
            for (int c = 0; c < NIN; ++c)
                pre += Win[(rg * 64 + br) * NIN + c] *
                       x[((size_t)(b0 + b) * TSTEPS + t) * NIN + c];
            const int qv = q8(tanhf(pre) * 127.f);
            // pack rows (2u,2u+1) of batch bb into one tagged dword
            const int qlo = __shfl(qv, ((lane >> 1) << 2) + (lane & 1), 64);
            const int qhi = __shfl(qv, ((lane >> 1) << 2) + 2 + (lane & 1), 64);
            if (lane < 32) {
                const int bb = lane & 1;
                const int u  = (w << 4) + (lane >> 1);   // 0..31 strip dword
                unsigned dv = (unsigned)(qlo & 0xff) |
                              ((unsigned)(qhi & 0xff) << 8) | (tg1 << 16);
                st1_uc(hbn + g * 2048 + bb * 1024 + rg * 32 + u, dv);
            }
        }

        // ---- waves 2-7: rotating projection (parallel with final/store)
        if (t > 0 && rg == ((t - 1) & 31) && w >= 2) {
            const int pw = w - 2;                    // 0..5
            const int b  = pw / NOUT;                // 0..1
            const int k  = pw % NOUT;                // 0..2
            const float4* wo4 = (const float4*)(Wout + (size_t)k * RDIM);
            float a = 0.f;
#pragma unroll
            for (int j = 0; j < 8; ++j) {
                unsigned hv = hstage[par][b][(lane << 3) + j];
                float4 wf = wo4[(lane << 3) + j];
                a += (float)(int)(signed char)(hv & 0xff)         * wf.x;
                a += (float)(int)(signed char)((hv >> 8) & 0xff)  * wf.y;
                a += (float)(int)(signed char)((hv >> 16) & 0xff) * wf.z;
                a += (float)(int)(signed char)(hv >> 24)          * wf.w;
            }
#pragma unroll
            for (int off = 32; off >= 1; off >>= 1)
                a += __shfl_xor(a, off, 64);
            if (lane == 0)
                out[((size_t)(b0 + b) * TSTEPS + (t - 1)) * NOUT + k] =
                    a * (1.f / 127.f) + bout[k];
        }
        // No further barrier: red/hstage parity + next step's barrier order
        // all WAR pairs (reads at t complete before barrier(t+1); writes to
        // this parity resume only at t+2 after barrier(t+1)).
    }
}

extern "C" void kernel_launch(void* const* d_in, const int* in_sizes, int n_in,
                              void* d_out, int out_size, void* d_ws, size_t ws_size,
                              hipStream_t stream) {
    const float* x    = (const float*)d_in[0];
    const float* Win  = (const float*)d_in[1];
    const float* W    = (const float*)d_in[2];
    const float* Wout = (const float*)d_in[3];
    const float* bout = (const float*)d_in[4];
    float* out = (float*)d_out;
    unsigned* wsu = (unsigned*)d_ws;

    // zero tagged-h buffers (tag0 + zero payload = valid h0), ~128 KB
    hipMemsetAsync(d_ws, 0, (size_t)WS_USED_DW * sizeof(unsigned), stream);

    // allow 128 KB dynamic LDS (idempotent; same work every call)
    hipFuncSetAttribute((const void*)esn_persist,
                        hipFuncAttributeMaxDynamicSharedMemorySize, 131072);

    void* args[] = {(void*)&W, (void*)&Win, (void*)&x, (void*)&Wout, (void*)&bout,
                    (void*)&wsu, (void*)&out};
    hipError_t e = hipLaunchCooperativeKernel((const void*)esn_persist,
                                              dim3(NBLK), dim3(NTHR),
                                              args, 131072, stream);
    if (e != hipSuccess) {
        // Fallback: plain launch (256 blocks, 1/CU with ~150KB LDS -> all
        // co-resident; bounded spins guarantee no hang regardless).
        esn_persist<<<dim3(NBLK), dim3(NTHR), 131072, stream>>>(
            W, Win, x, Wout, bout, wsu, out);
    }
}

// Round 6
// 6682.785 us; speedup vs baseline: 1.8092x; 1.1487x over previous
//
#include <hip/hip_runtime.h>
#include <math.h>

// ESN reservoir, persistent kernel, round 24: r23 structure (k-split waves,
// one barrier/step) with the LDS pipe fixed.
//
// r23 post-mortem (7677us, +13x bank conflicts = 8.6e8): W read pattern put
// the 8 rgrp lanes at 2048B stride = same bank quad => 8-way conflict on
// every ds_read_b128 (~1700cy/block-step); 16 ds_bpermute/thread added
// ~600cy more LDS pressure. Structure not refuted - implementation was.
//
// r24 changes (only these):
//  1. T2 XOR-swizzle on W LDS: granule gidx of row stored at
//     gidx ^ (((row>>3)&7)<<1). At read, row>>3 == rgrp => the 8 formerly
//     colliding lanes hit 8 distinct 32B slots = 32 banks, conflict-free.
//     Write side: constant per-wave XOR (row>>3 == w), bijective, stays
//     conflict-free.
//  2. h window via the hstage LDS round-trip that already exists for the
//     projection (wave w's lanes hold exactly payload dwords [64w,64w+64)
//     = its own k-slice): ds_write (already there) + 4x ds_read_b128
//     (broadcast + 2-way = free), wave-lockstep so NO barrier. Replaces
//     16 ds_bpermute.
//
// Everything else r23-verbatim: tagged protocol (dword = 2x int8 + tag16;
// store atomicity certifies payload), per-lane single-producer poll, fold
// via shfl_xor, ONE __syncthreads/step, waves 0-1 final+tanh+tagged stores,
// waves 2-7 rotating projection, parity double-buffered red/hstage (WAR
// ordered by the per-step barrier), bounded spins (never hang), int32 dot
// exact => bit-identical h trajectory.

#define RDIM   2048
#define BATCH  16
#define TSTEPS 2048
#define NIN    3
#define NOUT   3
#define NBLK   256
#define NTHR   512

typedef unsigned u32x2 __attribute__((ext_vector_type(2)));

// workspace layout (dwords)
#define HT0_DW     0            // [8 groups][2 batches][1024] tagged h dwords
#define HT1_DW     16384
#define WS_USED_DW 32768

#define POLL_MAX   (1L << 16)

__device__ __forceinline__ void st1_uc(unsigned* p, unsigned v) {
    asm volatile("global_store_dword %0, %1, off sc0 sc1" :: "v"(p), "v"(v) : "memory");
}

__device__ __forceinline__ int q8(float v) {          // round, clamp [-127,127]
    float c = fminf(127.f, fmaxf(-127.f, v));
    return (int)__builtin_rintf(c);
}
__device__ __forceinline__ unsigned pack4(int a, int b, int c, int d) {
    return (a & 0xff) | ((b & 0xff) << 8) | ((c & 0xff) << 16) | ((d & 0xff) << 24);
}
__device__ __forceinline__ int dot4i(unsigned a, unsigned b, int c) {
#if __has_builtin(__builtin_amdgcn_sdot4)
    return __builtin_amdgcn_sdot4((int)a, (int)b, c, false);
#else
    c += (int)(signed char)(a) * (int)(signed char)(b);
    c += (int)(signed char)(a >> 8)  * (int)(signed char)(b >> 8);
    c += (int)(signed char)(a >> 16) * (int)(signed char)(b >> 16);
    c += (int)(signed char)(a >> 24) * (int)(signed char)(b >> 24);
    return c;
#endif
}
__device__ __forceinline__ int dot16(uint4 wq, uint4 hq, int c) {
    c = dot4i(wq.x, hq.x, c);
    c = dot4i(wq.y, hq.y, c);
    c = dot4i(wq.z, hq.z, c);
    c = dot4i(wq.w, hq.w, c);
    return c;
}

extern "C" __global__ void __launch_bounds__(NTHR, 1) esn_persist(
    const float* __restrict__ W,       // [R,R] fp32
    const float* __restrict__ Win,     // [R,3]
    const float* __restrict__ x,       // [B,T,3]
    const float* __restrict__ Wout,    // [3,R]
    const float* __restrict__ bout,    // [3]
    unsigned* wsu,                     // workspace (dwords, see layout)
    float* __restrict__ out)           // [B,T,3]
{
    __shared__ int red[2][8][8][17];               // [par][wave][rgrp][rr*2+b] padded
    __shared__ __align__(16) unsigned hstage[2][2][512];  // [par][batch][payload dw]
    __shared__ float wscale[64];                   // per-row W scale (m/127)
    extern __shared__ unsigned wlds[];             // 128 KB: W int8, swizzled granules

    const int tid  = threadIdx.x;
    const int lane = tid & 63;
    const int w    = tid >> 6;               // wave 0..7
    const int blk  = blockIdx.x;
    const int rg   = blk & 31;               // rows rg*64..+64
    const int g    = blk >> 5;               // batches g*2..+2
    const int b0    = g * 2;
    const int kslot = lane >> 3;             // 0..7: k sub-slice within wave
    const int rgrp  = lane & 7;              // 0..7: row octet within block

    // ---- one-time: quantize W rows -> LDS int8 (per-row scale), swizzled ----
    // granule g of in-block row r stored at g ^ (((r>>3)&7)<<1); here r>>3 == w.
#pragma unroll
    for (int rr = 0; rr < 8; ++rr) {
        const int   row = rg * 64 + w * 8 + rr;
        const float4* Wr = (const float4*)(W + (size_t)row * RDIM);
        float m = 0.f;
#pragma unroll
        for (int j = 0; j < 8; ++j) {        // lane covers 8 float4 = 32 elems
            float4 v = Wr[j * 64 + lane];
            m = fmaxf(m, fmaxf(fmaxf(fabsf(v.x), fabsf(v.y)),
                               fmaxf(fabsf(v.z), fabsf(v.w))));
        }
#pragma unroll
        for (int off = 32; off >= 1; off >>= 1)
            m = fmaxf(m, __shfl_xor(m, off, 64));
        const float inv = (m > 0.f) ? 127.f / m : 0.f;
        if (lane == 0) wscale[w * 8 + rr] = (m > 0.f) ? m / 127.f : 0.f;
#pragma unroll
        for (int j = 0; j < 8; ++j) {
            float4 v = Wr[j * 64 + lane];
            const int gsw = (j * 16 + (lane >> 2)) ^ (w << 1);   // swizzled granule
            wlds[(w * 8 + rr) * 512 + gsw * 4 + (lane & 3)] =
                pack4(q8(v.x * inv), q8(v.y * inv), q8(v.z * inv), q8(v.w * inv));
        }
    }
    __syncthreads();

    unsigned* const ht0 = wsu + HT0_DW;
    unsigned* const ht1 = wsu + HT1_DW;

    for (int t = 0; t <= TSTEPS; ++t) {
        unsigned* const hb  = (t & 1) ? ht1 : ht0;   // tags == t live here
        unsigned* const hbn = (t & 1) ? ht0 : ht1;   // t+1 stores go here
        const unsigned tg  = (unsigned)t & 0xffffu;
        const unsigned tg1 = (unsigned)(t + 1) & 0xffffu;
        const int par = t & 1;

        // ---- poll: lane waits on its OWN 4-value window (1 producer/batch)
        // tagged uint2 per batch at [128w + 2*lane]; memset zeros = valid h0.
        u32x2 ta, tb;
        {
            const unsigned* pA = hb + g * 2048 +        128 * w + 2 * lane;
            const unsigned* pB = hb + g * 2048 + 1024 + 128 * w + 2 * lane;
            long r = 0;
            for (;;) {
                asm volatile("global_load_dwordx2 %0, %2, off sc0 sc1\n\t"
                             "global_load_dwordx2 %1, %3, off sc0 sc1\n\t"
                             "s_waitcnt vmcnt(0)"
                             : "=&v"(ta), "=&v"(tb) : "v"(pA), "v"(pB) : "memory");
                bool ok = (ta[0] >> 16) == tg && (ta[1] >> 16) == tg &&
                          (tb[0] >> 16) == tg && (tb[1] >> 16) == tg;
                if (ok || r > POLL_MAX) break;   // per-lane exit; never hangs
                ++r;
                if (r > 64) __builtin_amdgcn_s_sleep(1);
            }
        }
        // detag: payload dword (4 int8 h values) per batch -> hstage
        const unsigned pdA = (ta[0] & 0xffffu) | (ta[1] << 16);
        const unsigned pdB = (tb[0] & 0xffffu) | (tb[1] << 16);
        hstage[par][0][(w << 6) + lane] = pdA;
        hstage[par][1][(w << 6) + lane] = pdB;

        if (t < TSTEPS) {
            // ---- wave-local h window reassembly from hstage (wave w's lanes
            // hold exactly payload dwords [64w,64w+64) = its own k-slice);
            // wave is lockstep => ds_write above completes (lgkmcnt) before
            // these reads issue — no barrier. Broadcast + 2-way = free.
            const uint4* hwA = (const uint4*)&hstage[par][0][(w << 6) + (kslot << 3)];
            const uint4* hwB = (const uint4*)&hstage[par][1][(w << 6) + (kslot << 3)];
            const uint4 hA0 = hwA[0], hA1 = hwA[1];
            const uint4 hB0 = hwB[0], hB1 = hwB[1];

            // ---- partial dot: rows [8*rgrp..+8), k [256w+32*kslot..+32)
            // swizzled granule base: bits1-3 XORed with rgrp => conflict-free.
            int acc[8][2];
#pragma unroll
            for (int rr = 0; rr < 8; ++rr) { acc[rr][0] = 0; acc[rr][1] = 0; }
            const uint4* w4p = (const uint4*)wlds;
            const int gbase = (w << 4) + (((kslot ^ rgrp) & 7) << 1);
#pragma unroll
            for (int rr = 0; rr < 8; ++rr) {
                const int gi = (((rgrp << 3) + rr) << 7) + gbase;
                uint4 w0 = w4p[gi];
                uint4 w1 = w4p[gi + 1];
                acc[rr][0] = dot16(w0, hA0, acc[rr][0]);
                acc[rr][0] = dot16(w1, hA1, acc[rr][0]);
                acc[rr][1] = dot16(w0, hB0, acc[rr][1]);
                acc[rr][1] = dot16(w1, hB1, acc[rr][1]);
            }
            // ---- fold kslot (lane bits 3..5); int add order-exact
#pragma unroll
            for (int rr = 0; rr < 8; ++rr)
#pragma unroll
                for (int b = 0; b < 2; ++b) {
                    int a = acc[rr][b];
                    a += __shfl_xor(a, 8, 64);
                    a += __shfl_xor(a, 16, 64);
                    a += __shfl_xor(a, 32, 64);
                    acc[rr][b] = a;
                }
            if (lane < 8) {                          // lane == rgrp, kslot 0
#pragma unroll
                for (int rr = 0; rr < 8; ++rr) {
                    red[par][w][lane][(rr << 1)]     = acc[rr][0];
                    red[par][w][lane][(rr << 1) + 1] = acc[rr][1];
                }
            }
        }
        __syncthreads();                             // the ONE barrier/step

        // ---- waves 0-1: final 8-way sum, tanh, tagged stores (r21 wire fmt)
        if (t < TSTEPS && tid < 128) {
            const int br = tid >> 1;                 // in-block row 0..63
            const int b  = tid & 1;
            int s = 0;
#pragma unroll
            for (int wp = 0; wp < 8; ++wp)
                s += red[par][wp][br >> 3][((br & 7) << 1) + b];
            float pre = (float)s * wscale[br] * (1.f / 127.f);
#pragma unroll
            for (int c = 0; c < NIN; ++c)
                pre += Win[(rg * 64 + br) * NIN + c] *
                       x[((size_t)(b0 + b) * TSTEPS + t) * NIN + c];
            const int qv = q8(tanhf(pre) * 127.f);
            // pack rows (2u,2u+1) of batch bb into one tagged dword
            const int qlo = __shfl(qv, ((lane >> 1) << 2) + (lane & 1), 64);
            const int qhi = __shfl(qv, ((lane >> 1) << 2) + 2 + (lane & 1), 64);
            if (lane < 32) {
                const int bb = lane & 1;
                const int u  = (w << 4) + (lane >> 1);   // 0..31 strip dword
                unsigned dv = (unsigned)(qlo & 0xff) |
                              ((unsigned)(qhi & 0xff) << 8) | (tg1 << 16);
                st1_uc(hbn + g * 2048 + bb * 1024 + rg * 32 + u, dv);
            }
        }

        // ---- waves 2-7: rotating projection (parallel with final/store)
        if (t > 0 && rg == ((t - 1) & 31) && w >= 2) {
            const int pw = w - 2;                    // 0..5
            const int b  = pw / NOUT;                // 0..1
            const int k  = pw % NOUT;                // 0..2
            const float4* wo4 = (const float4*)(Wout + (size_t)k * RDIM);
            float a = 0.f;
#pragma unroll
            for (int j = 0; j < 8; ++j) {
                unsigned hv = hstage[par][b][(lane << 3) + j];
                float4 wf = wo4[(lane << 3) + j];
                a += (float)(int)(signed char)(hv & 0xff)         * wf.x;
                a += (float)(int)(signed char)((hv >> 8) & 0xff)  * wf.y;
                a += (float)(int)(signed char)((hv >> 16) & 0xff) * wf.z;
                a += (float)(int)(signed char)(hv >> 24)          * wf.w;
            }
#pragma unroll
            for (int off = 32; off >= 1; off >>= 1)
                a += __shfl_xor(a, off, 64);
            if (lane == 0)
                out[((size_t)(b0 + b) * TSTEPS + (t - 1)) * NOUT + k] =
                    a * (1.f / 127.f) + bout[k];
        }
        // WAR safety: reads of red/hstage[par] at step t happen before
        // barrier(t+1); next writes to this parity happen at t+2 after
        // barrier(t+1) => ordered. hstage writes(t) vs cross-wave reads(t)
        // ordered by barrier(t); intra-wave window reads are lockstep-safe.
    }
}

extern "C" void kernel_launch(void* const* d_in, const int* in_sizes, int n_in,
                              void* d_out, int out_size, void* d_ws, size_t ws_size,
                              hipStream_t stream) {
    const float* x    = (const float*)d_in[0];
    const float* Win  = (const float*)d_in[1];
    const float* W    = (const float*)d_in[2];
    const float* Wout = (const float*)d_in[3];
    const float* bout = (const float*)d_in[4];
    float* out = (float*)d_out;
    unsigned* wsu = (unsigned*)d_ws;

    // zero tagged-h buffers (tag0 + zero payload = valid h0), ~128 KB
    hipMemsetAsync(d_ws, 0, (size_t)WS_USED_DW * sizeof(unsigned), stream);

    // allow 128 KB dynamic LDS (idempotent; same work every call)
    hipFuncSetAttribute((const void*)esn_persist,
                        hipFuncAttributeMaxDynamicSharedMemorySize, 131072);

    void* args[] = {(void*)&W, (void*)&Win, (void*)&x, (void*)&Wout, (void*)&bout,
                    (void*)&wsu, (void*)&out};
    hipError_t e = hipLaunchCooperativeKernel((const void*)esn_persist,
                                              dim3(NBLK), dim3(NTHR),
                                              args, 131072, stream);
    if (e != hipSuccess) {
        // Fallback: plain launch (256 blocks, 1/CU with ~150KB LDS -> all
        // co-resident; bounded spins guarantee no hang regardless).
        esn_persist<<<dim3(NBLK), dim3(NTHR), 131072, stream>>>(
            W, Win, x, Wout, bout, wsu, out);
    }
}